// Round 1
// baseline (166.594 us; speedup 1.0000x reference)
//
#include <hip/hip_runtime.h>

#define NNODES 10000
#define NEDGES 4096
#define INF 300
#define OUTF 150
#define EPB 8            // edges per block: W/b L2 traffic amortization
#define EDGE_THREADS 192 // 3 waves; lanes 0..149 compute, 150..157 do counts

__global__ __launch_bounds__(EDGE_THREADS) void edge_msg_kernel(
    const float* __restrict__ feat, const float* __restrict__ efeat,
    const float* __restrict__ W, const float* __restrict__ B,
    const int* __restrict__ src, const int* __restrict__ dst,
    float* __restrict__ sums, float* __restrict__ cnts)
{
    __shared__ float hA[EPB][INF];
    __shared__ float s_ef[EPB];
    __shared__ int   s_dst[EPB];
    __shared__ int   s_src[EPB];

    const int tid = threadIdx.x;
    const int e0  = blockIdx.x * EPB;

    if (tid < EPB) {
        const int e = e0 + tid;
        s_src[tid] = src[e];
        s_dst[tid] = dst[e];
        s_ef[tid]  = efeat[e];
    }
    __syncthreads();

    // Stage 8 gathered feature rows into LDS (coalesced within each row).
    #pragma unroll
    for (int el = 0; el < EPB; ++el) {
        const float* row = feat + (long)s_src[el] * INF;
        for (int i = tid; i < INF; i += EDGE_THREADS)
            hA[el][i] = row[i];
    }
    __syncthreads();

    if (tid < OUTF) {
        float accW[EPB], accB[EPB];
        #pragma unroll
        for (int e = 0; e < EPB; ++e) { accW[e] = 0.f; accB[e] = 0.f; }

        const float* Wc = W + tid;  // column o = tid; stride OUTF
        const float* Bc = B + tid;
        #pragma unroll 4
        for (int i = 0; i < INF; ++i) {
            const float w  = Wc[(long)i * OUTF];   // coalesced across lanes
            const float bv = Bc[(long)i * OUTF];
            #pragma unroll
            for (int e = 0; e < EPB; ++e) {
                const float h = hA[e][i];          // LDS broadcast, no conflict
                accW[e] = fmaf(h, w,  accW[e]);
                accB[e] = fmaf(h, bv, accB[e]);
            }
        }
        // msgs[e,o] = efeat[e]*(h@W) + (h@b);  scatter-add to dst
        #pragma unroll
        for (int e = 0; e < EPB; ++e) {
            const float msg = fmaf(s_ef[e], accW[e], accB[e]);
            atomicAdd(&sums[(long)s_dst[e] * OUTF + tid], msg);
        }
    } else if (tid < OUTF + EPB) {
        atomicAdd(&cnts[s_dst[tid - OUTF]], 1.0f);
    }
}

__global__ __launch_bounds__(256) void finalize_kernel(
    const float* __restrict__ sums, const float* __restrict__ cnts,
    const float* __restrict__ bias, float* __restrict__ out)
{
    const int idx = blockIdx.x * blockDim.x + threadIdx.x;
    const int total = NNODES * OUTF;
    if (idx < total) {
        const int n = idx / OUTF;        // magic-div by compiler
        const int o = idx - n * OUTF;
        const float c = cnts[n];         // broadcast within row, L1-cached
        const float m = sums[idx] / fmaxf(c, 1.0f);
        const float v = m + bias[o];
        out[idx] = v > 0.f ? v : 0.f;
    }
}

extern "C" void kernel_launch(void* const* d_in, const int* in_sizes, int n_in,
                              void* d_out, int out_size, void* d_ws, size_t ws_size,
                              hipStream_t stream) {
    const float* feat  = (const float*)d_in[0];
    const float* efeat = (const float*)d_in[1];
    const float* W     = (const float*)d_in[2];
    const float* B     = (const float*)d_in[3];
    const float* bias  = (const float*)d_in[4];
    const int*   src   = (const int*)d_in[5];
    const int*   dst   = (const int*)d_in[6];
    float* out  = (float*)d_out;

    float* sums = (float*)d_ws;                          // [NNODES*OUTF]
    float* cnts = sums + (size_t)NNODES * OUTF;          // [NNODES]

    hipMemsetAsync(d_ws, 0, ((size_t)NNODES * OUTF + NNODES) * sizeof(float), stream);

    edge_msg_kernel<<<NEDGES / EPB, EDGE_THREADS, 0, stream>>>(
        feat, efeat, W, B, src, dst, sums, cnts);

    const int total = NNODES * OUTF;
    finalize_kernel<<<(total + 255) / 256, 256, 0, stream>>>(sums, cnts, bias, out);
}

// Round 2
// 111.806 us; speedup vs baseline: 1.4900x; 1.4900x over previous
//
#include <hip/hip_runtime.h>

#define NNODES 10000
#define NEDGES 4096
#define INF 300
#define OUTF 150
#define EPB 16                       // edges per block
#define NGROUPS (NEDGES / EPB)       // 256 edge groups
#define SPLITK 6                     // K split; 300/6 = 50
#define KCHUNK (INF / SPLITK)        // 50
#define EDGE_THREADS 192             // lanes 0..149 compute, 150..165 counts

__global__ __launch_bounds__(EDGE_THREADS) void edge_msg_kernel(
    const float* __restrict__ feat, const float* __restrict__ efeat,
    const float* __restrict__ W, const float* __restrict__ B,
    const int* __restrict__ src, const int* __restrict__ dst,
    float* __restrict__ sums, float* __restrict__ cnts)
{
    __shared__ float hA[EPB][KCHUNK];
    __shared__ float s_ef[EPB];
    __shared__ int   s_dst[EPB];
    __shared__ int   s_src[EPB];

    const int tid = threadIdx.x;
    const int kc  = blockIdx.x / NGROUPS;   // 0..SPLITK-1 (consecutive blocks share kc)
    const int grp = blockIdx.x - kc * NGROUPS;
    const int e0  = grp * EPB;
    const int k0  = kc * KCHUNK;

    if (tid < EPB) {
        const int e = e0 + tid;
        s_src[tid] = src[e];
        s_dst[tid] = dst[e];
        s_ef[tid]  = efeat[e];
    }
    __syncthreads();

    // Stage this block's K-chunk of the 16 gathered feature rows into LDS.
    for (int idx = tid; idx < EPB * KCHUNK; idx += EDGE_THREADS) {
        const int el = idx / KCHUNK;
        const int i  = idx - el * KCHUNK;
        hA[el][i] = feat[(long)s_src[el] * INF + k0 + i];
    }
    __syncthreads();

    if (tid < OUTF) {
        float accW[EPB], accB[EPB];
        #pragma unroll
        for (int e = 0; e < EPB; ++e) { accW[e] = 0.f; accB[e] = 0.f; }

        const float* Wc = W + (long)k0 * OUTF + tid;  // column o = tid
        const float* Bc = B + (long)k0 * OUTF + tid;
        #pragma unroll 2
        for (int i = 0; i < KCHUNK; ++i) {
            const float w  = Wc[(long)i * OUTF];      // coalesced across lanes
            const float bv = Bc[(long)i * OUTF];
            #pragma unroll
            for (int e = 0; e < EPB; ++e) {
                const float h = hA[e][i];             // LDS broadcast
                accW[e] = fmaf(h, w,  accW[e]);
                accB[e] = fmaf(h, bv, accB[e]);
            }
        }
        // partial msg for this K-chunk: ef*(h@W)_part + (h@b)_part — linear, so
        // split-K partials sum correctly via atomicAdd.
        #pragma unroll
        for (int e = 0; e < EPB; ++e) {
            const float msg = fmaf(s_ef[e], accW[e], accB[e]);
            atomicAdd(&sums[(long)s_dst[e] * OUTF + tid], msg);
        }
    } else if (kc == 0 && tid < OUTF + EPB) {
        atomicAdd(&cnts[s_dst[tid - OUTF]], 1.0f);   // count each edge once
    }
}

__global__ __launch_bounds__(256) void finalize_kernel(
    const float* __restrict__ sums, const float* __restrict__ cnts,
    const float* __restrict__ bias, float* __restrict__ out)
{
    const int idx = blockIdx.x * blockDim.x + threadIdx.x;
    const int total = NNODES * OUTF;
    if (idx < total) {
        const int n = idx / OUTF;
        const int o = idx - n * OUTF;
        const float c = cnts[n];
        const float m = sums[idx] / fmaxf(c, 1.0f);
        const float v = m + bias[o];
        out[idx] = v > 0.f ? v : 0.f;
    }
}

extern "C" void kernel_launch(void* const* d_in, const int* in_sizes, int n_in,
                              void* d_out, int out_size, void* d_ws, size_t ws_size,
                              hipStream_t stream) {
    const float* feat  = (const float*)d_in[0];
    const float* efeat = (const float*)d_in[1];
    const float* W     = (const float*)d_in[2];
    const float* B     = (const float*)d_in[3];
    const float* bias  = (const float*)d_in[4];
    const int*   src   = (const int*)d_in[5];
    const int*   dst   = (const int*)d_in[6];
    float* out  = (float*)d_out;

    float* sums = (float*)d_ws;                          // [NNODES*OUTF]
    float* cnts = sums + (size_t)NNODES * OUTF;          // [NNODES]

    hipMemsetAsync(d_ws, 0, ((size_t)NNODES * OUTF + NNODES) * sizeof(float), stream);

    edge_msg_kernel<<<NGROUPS * SPLITK, EDGE_THREADS, 0, stream>>>(
        feat, efeat, W, B, src, dst, sums, cnts);

    const int total = NNODES * OUTF;
    finalize_kernel<<<(total + 255) / 256, 256, 0, stream>>>(sums, cnts, bias, out);
}